// Round 13
// baseline (1076.964 us; speedup 1.0000x reference)
//
#include <hip/hip_runtime.h>
#include <math.h>

// ---------------------------------------------------------------------------
// PermutedNetwork, R13 = R12 (175.7us) + register-prefetched weight staging
// in deform_patch. R12 model: phase2 is latency-bound on the per-k
// barrier->global-load->barrier weight stage (~600-900cy x9 on every wave's
// critical path). Prefetch k+1 weights into regs while computing k; k=0's
// load hides under phase 1. Same barriers, latency off the critical path.
// ---------------------------------------------------------------------------

// ---- Weight transpose: w[o][c][k] -> wT[k][c][o] (run once, tiny).
template <int CIN, int COUT>
__global__ void wtrans(const float* __restrict__ w, float* __restrict__ wT) {
  int t = blockIdx.x * 256 + threadIdx.x;
  if (t >= 9 * CIN * COUT) return;
  int k = t / (CIN * COUT);
  int r = t % (CIN * COUT);
  int c = r / COUT;
  int o = r % COUT;
  wT[t] = w[(o * CIN + c) * 9 + k];
}

// ---- Layer 1: fused offset-conv + deform + relu, CIN=1. 2 pixels/thread.
__global__ void deform1_fused(const float* __restrict__ x,    // [64,96,96]
                              const float* __restrict__ woff, // [18,1,3,3]
                              const float* __restrict__ boff, // [18]
                              const float* __restrict__ w1,   // [16,1,3,3]
                              const float* __restrict__ b1,   // [16]
                              float* __restrict__ out) {      // [64,16,96,96]
  const int H = 96, W = 96, HW = H * W;
  __shared__ float wos[9 * 18];
  __shared__ __align__(16) float ws1[9 * 16];
  for (int t = threadIdx.x; t < 9 * 18; t += 256) { int k = t / 18, tc = t % 18; wos[t] = woff[tc * 9 + k]; }
  for (int t = threadIdx.x; t < 9 * 16; t += 256) { int k = t / 16, o = t % 16; ws1[t] = w1[o * 9 + k]; }
  __syncthreads();

  int gid = blockIdx.x * 256 + threadIdx.x;
  int p2 = gid % (HW / 2);
  int b  = gid / (HW / 2);
  int xi0 = (2 * p2) % W, yi = (2 * p2) / W;
  const float* xb = x + (size_t)b * HW;

  float v[3][4];
#pragma unroll
  for (int r = 0; r < 3; ++r) {
    int yy = yi + r - 1;
    float my = (yy >= 0 && yy < H) ? 1.f : 0.f;
    int cy = min(max(yy, 0), H - 1);
#pragma unroll
    for (int c = 0; c < 4; ++c) {
      int xx = xi0 + c - 1;
      float mx = (xx >= 0 && xx < W) ? 1.f : 0.f;
      int cx = min(max(xx, 0), W - 1);
      v[r][c] = xb[cy * W + cx] * (my * mx);
    }
  }

  float off0[18], off1[18];
#pragma unroll
  for (int tc = 0; tc < 18; ++tc) { float bb = boff[tc]; off0[tc] = bb; off1[tc] = bb; }
#pragma unroll
  for (int r = 0; r < 3; ++r)
#pragma unroll
    for (int c = 0; c < 3; ++c) {
      float t0 = v[r][c], t1 = v[r][c + 1];
      const float2* wv = (const float2*)&wos[(r * 3 + c) * 18];
#pragma unroll
      for (int tt = 0; tt < 9; ++tt) {
        float2 ww = wv[tt];
        off0[2 * tt]     = fmaf(ww.x, t0, off0[2 * tt]);
        off0[2 * tt + 1] = fmaf(ww.y, t0, off0[2 * tt + 1]);
        off1[2 * tt]     = fmaf(ww.x, t1, off1[2 * tt]);
        off1[2 * tt + 1] = fmaf(ww.y, t1, off1[2 * tt + 1]);
      }
    }

  float acc0[16], acc1[16];
#pragma unroll
  for (int o = 0; o < 16; ++o) { float bb = b1[o]; acc0[o] = bb; acc1[o] = bb; }

#pragma unroll
  for (int k = 0; k < 9; ++k) {
    int dky = k / 3 - 1, dkx = k % 3 - 1;
    float val0, val1;
    {
      float py = (float)(yi + dky) + off0[2 * k];
      float px = (float)(xi0 + dkx) + off0[2 * k + 1];
      float y0f = floorf(py), x0f = floorf(px);
      float fy = py - y0f, fx = px - x0f;
      int y0 = (int)y0f, x0 = (int)x0f, y1 = y0 + 1, x1 = x0 + 1;
      float vy0 = (y0 >= 0 && y0 < H) ? 1.f : 0.f;
      float vy1 = (y1 >= 0 && y1 < H) ? 1.f : 0.f;
      float vx0 = (x0 >= 0 && x0 < W) ? 1.f : 0.f;
      float vx1 = (x1 >= 0 && x1 < W) ? 1.f : 0.f;
      float w00 = (1.f - fy) * (1.f - fx) * vy0 * vx0;
      float w01 = (1.f - fy) * fx * vy0 * vx1;
      float w10 = fy * (1.f - fx) * vy1 * vx0;
      float w11 = fy * fx * vy1 * vx1;
      int cy0 = min(max(y0, 0), H - 1), cy1 = min(max(y1, 0), H - 1);
      int cx0 = min(max(x0, 0), W - 1), cx1 = min(max(x1, 0), W - 1);
      float a = xb[cy0 * W + cx0], bb = xb[cy0 * W + cx1];
      float c = xb[cy1 * W + cx0], d = xb[cy1 * W + cx1];
      val0 = w00 * a + w01 * bb + w10 * c + w11 * d;
    }
    {
      float py = (float)(yi + dky) + off1[2 * k];
      float px = (float)(xi0 + 1 + dkx) + off1[2 * k + 1];
      float y0f = floorf(py), x0f = floorf(px);
      float fy = py - y0f, fx = px - x0f;
      int y0 = (int)y0f, x0 = (int)x0f, y1 = y0 + 1, x1 = x0 + 1;
      float vy0 = (y0 >= 0 && y0 < H) ? 1.f : 0.f;
      float vy1 = (y1 >= 0 && y1 < H) ? 1.f : 0.f;
      float vx0 = (x0 >= 0 && x0 < W) ? 1.f : 0.f;
      float vx1 = (x1 >= 0 && x1 < W) ? 1.f : 0.f;
      float w00 = (1.f - fy) * (1.f - fx) * vy0 * vx0;
      float w01 = (1.f - fy) * fx * vy0 * vx1;
      float w10 = fy * (1.f - fx) * vy1 * vx0;
      float w11 = fy * fx * vy1 * vx1;
      int cy0 = min(max(y0, 0), H - 1), cy1 = min(max(y1, 0), H - 1);
      int cx0 = min(max(x0, 0), W - 1), cx1 = min(max(x1, 0), W - 1);
      float a = xb[cy0 * W + cx0], bb = xb[cy0 * W + cx1];
      float c = xb[cy1 * W + cx0], d = xb[cy1 * W + cx1];
      val1 = w00 * a + w01 * bb + w10 * c + w11 * d;
    }
    const float4* wv = (const float4*)&ws1[k * 16];
#pragma unroll
    for (int q = 0; q < 4; ++q) {
      float4 w4 = wv[q];
      acc0[4 * q + 0] = fmaf(w4.x, val0, acc0[4 * q + 0]);
      acc0[4 * q + 1] = fmaf(w4.y, val0, acc0[4 * q + 1]);
      acc0[4 * q + 2] = fmaf(w4.z, val0, acc0[4 * q + 2]);
      acc0[4 * q + 3] = fmaf(w4.w, val0, acc0[4 * q + 3]);
      acc1[4 * q + 0] = fmaf(w4.x, val1, acc1[4 * q + 0]);
      acc1[4 * q + 1] = fmaf(w4.y, val1, acc1[4 * q + 1]);
      acc1[4 * q + 2] = fmaf(w4.z, val1, acc1[4 * q + 2]);
      acc1[4 * q + 3] = fmaf(w4.w, val1, acc1[4 * q + 3]);
    }
  }

  float* op = out + (size_t)b * 16 * HW + (size_t)yi * W + xi0;
#pragma unroll
  for (int o = 0; o < 16; ++o) {
    float2 r = make_float2(fmaxf(acc0[o], 0.f), fmaxf(acc1[o], 0.f));
    *(float2*)(op + (size_t)o * HW) = r;
  }
}

// ---- 2x2 maxpool, NCHW in -> NHWC out.
template <int C, int HI>
__global__ void pool_nchw_to_nhwc(const float* __restrict__ in,  // [B,C,HI,HI]
                                  float* __restrict__ out) {     // [B,HO,HO,C]
  const int HO = HI / 2, C4 = C / 4;
  int gid = blockIdx.x * blockDim.x + threadIdx.x;
  if (gid >= 64 * HO * HO * C4) return;
  int c4 = gid % C4;
  int t = gid / C4;
  int x = t % HO; t /= HO;
  int y = t % HO;
  int b = t / HO;
  float4 r;
  float* rp = &r.x;
#pragma unroll
  for (int cc = 0; cc < 4; ++cc) {
    int c = c4 * 4 + cc;
    const float* p = in + ((size_t)(b * C + c) * HI + 2 * y) * HI + 2 * x;
    rp[cc] = fmaxf(fmaxf(p[0], p[1]), fmaxf(p[HI], p[HI + 1]));
  }
  *(float4*)(out + (((size_t)b * HO + y) * HO + x) * C + c4 * 4) = r;
}

// ---- 3x3 conv for offsets: NHWC in, PADDED NHWC out [B,H,W,20].
template <int CIN, int COUT, int NSPLIT>
__global__ __launch_bounds__(256, 4)
void conv3x3_off(const float* __restrict__ in,  // [B,H,W,CIN]
                 const float* __restrict__ w,   // [COUT,CIN,3,3]
                 const float* __restrict__ bias,
                 float* __restrict__ out,       // [B,H,W,20]
                 int B, int H, int W) {
  constexpr int OC = COUT / NSPLIT;
  __shared__ float ws[9 * CIN * OC];
  int obase = blockIdx.y * OC;
  for (int t = threadIdx.x; t < 9 * CIN * OC; t += 256) {
    int k = t / (CIN * OC); int r = t % (CIN * OC);
    int c = r / OC; int o = r % OC;
    ws[t] = w[((obase + o) * CIN + c) * 9 + k];
  }
  __syncthreads();

  int gid = blockIdx.x * 256 + threadIdx.x;
  if (gid >= B * H * W) return;
  int x = gid % W; int t0 = gid / W; int y = t0 % H; int b = t0 / H;
  int HW = H * W;
  const float* inb = in + (size_t)b * HW * CIN;

  float acc[OC];
#pragma unroll
  for (int o = 0; o < OC; ++o) acc[o] = bias[obase + o];

#pragma unroll
  for (int ky = 0; ky < 3; ++ky) {
    int yy = y + ky - 1;
    if (yy < 0 || yy >= H) continue;
#pragma unroll
    for (int kx = 0; kx < 3; ++kx) {
      int xx = x + kx - 1;
      if (xx < 0 || xx >= W) continue;
      const float4* p4 = (const float4*)(inb + ((size_t)yy * W + xx) * CIN);
      int k = ky * 3 + kx;
#pragma unroll
      for (int c4 = 0; c4 < CIN / 4; ++c4) {
        float4 p = p4[c4];
        const float* pv = &p.x;
#pragma unroll
        for (int cc = 0; cc < 4; ++cc) {
          const float* wrow = &ws[(k * CIN + 4 * c4 + cc) * OC];
#pragma unroll
          for (int o = 0; o < OC; ++o) acc[o] = fmaf(wrow[o], pv[cc], acc[o]);
        }
      }
    }
  }

  float* op = out + (size_t)gid * 20 + obase;
#pragma unroll
  for (int o = 0; o < OC; ++o) op[o] = acc[o];
}

// ---- Two-phase patch-LDS deformable conv + ReLU (R12 structure +
// register-prefetched weight staging).
template <int CIN, int COUT, int HW_, int PX>
__global__ void deform_patch(const float* __restrict__ in,     // [B,H,W,CIN]
                             const float* __restrict__ off_in, // [B*HW,20]
                             const float* __restrict__ wT,     // [9][CIN][COUT]
                             const float* __restrict__ bias,
                             float* __restrict__ out) {        // [B,COUT,H,W]
  constexpr int H = HW_, W = HW_, HW = H * W;
  constexpr int QT = CIN / 4;
  static_assert(PX * QT == 256, "block mapping");
  constexpr int PSTR = 9 * CIN + 4;       // per-px float stride (16B aligned)
  constexpr int PP = PX / 2;              // pixel pairs
  constexpr int OG = 256 / PP;            // out-channel groups
  constexpr int OPG = COUT / OG;          // outs per group
  static_assert(OPG == 4, "phase2 mapping");
  constexpr int WN4 = CIN * COUT / 4;     // weight float4s per k (128 / 512)
  constexpr int NPRE = (WN4 + 255) / 256; // per-thread prefetch regs (1 / 2)

  __shared__ __align__(16) float offs[PX * 20];
  __shared__ __align__(16) float patch[PX * PSTR];
  __shared__ __align__(16) float wsk[CIN * COUT];

  const int pixbase = blockIdx.x * PX;    // global pixel index over B*HW
  const int b = pixbase / HW;
  const int p0_in_b = pixbase - b * HW;
  const float* inb = in + (size_t)b * HW * CIN;

  // prefetch k=0 weights into registers (latency hides under phase 1)
  float4 wpre[NPRE];
#pragma unroll
  for (int j = 0; j < NPRE; ++j) {
    int t = threadIdx.x + j * 256;
    if (t < WN4) wpre[j] = ((const float4*)wT)[t];
  }

  // stage offsets (contiguous)
  {
    const float4* src = (const float4*)(off_in + (size_t)pixbase * 20);
    for (int t = threadIdx.x; t < PX * 20 / 4; t += 256)
      ((float4*)offs)[t] = src[t];
  }
  __syncthreads();

  // ---- phase 1: build patches (lane map: px = tid/QT, q = tid%QT)
  {
    int px = threadIdx.x / QT;
    int q  = threadIdx.x % QT;
    int pib = p0_in_b + px;
    int yi = pib / W, xi = pib % W;
#pragma unroll
    for (int k = 0; k < 9; ++k) {
      float py = (float)(yi + k / 3 - 1) + offs[px * 20 + 2 * k];
      float pxx = (float)(xi + k % 3 - 1) + offs[px * 20 + 2 * k + 1];
      float y0f = floorf(py), x0f = floorf(pxx);
      float fy = py - y0f, fx = pxx - x0f;
      int y0 = (int)y0f, x0 = (int)x0f, y1 = y0 + 1, x1 = x0 + 1;
      float vy0 = (y0 >= 0 && y0 < H) ? 1.f : 0.f;
      float vy1 = (y1 >= 0 && y1 < H) ? 1.f : 0.f;
      float vx0 = (x0 >= 0 && x0 < W) ? 1.f : 0.f;
      float vx1 = (x1 >= 0 && x1 < W) ? 1.f : 0.f;
      float w00 = (1.f - fy) * (1.f - fx) * vy0 * vx0;
      float w01 = (1.f - fy) * fx * vy0 * vx1;
      float w10 = fy * (1.f - fx) * vy1 * vx0;
      float w11 = fy * fx * vy1 * vx1;
      int cy0 = min(max(y0, 0), H - 1), cy1 = min(max(y1, 0), H - 1);
      int cx0 = min(max(x0, 0), W - 1), cx1 = min(max(x1, 0), W - 1);
      float4 A  = *(const float4*)(inb + ((size_t)cy0 * W + cx0) * CIN + 4 * q);
      float4 Bv = *(const float4*)(inb + ((size_t)cy0 * W + cx1) * CIN + 4 * q);
      float4 Cv = *(const float4*)(inb + ((size_t)cy1 * W + cx0) * CIN + 4 * q);
      float4 Dv = *(const float4*)(inb + ((size_t)cy1 * W + cx1) * CIN + 4 * q);
      float4 val;
      val.x = w00 * A.x + w01 * Bv.x + w10 * Cv.x + w11 * Dv.x;
      val.y = w00 * A.y + w01 * Bv.y + w10 * Cv.y + w11 * Dv.y;
      val.z = w00 * A.z + w01 * Bv.z + w10 * Cv.z + w11 * Dv.z;
      val.w = w00 * A.w + w01 * Bv.w + w10 * Cv.w + w11 * Dv.w;
      *(float4*)&patch[px * PSTR + k * CIN + 4 * q] = val;
    }
  }
  __syncthreads();          // patches done; wpre(k=0) loads long since issued

  // write k=0 weights to LDS
#pragma unroll
  for (int j = 0; j < NPRE; ++j) {
    int t = threadIdx.x + j * 256;
    if (t < WN4) ((float4*)wsk)[t] = wpre[j];
  }
  __syncthreads();          // wsk = weights(k=0)

  // ---- phase 2: GEMM from LDS with prefetch of k+1 weights
  int pairIdx = threadIdx.x % PP;
  int og = threadIdx.x / PP;
  int obase = og * OPG;
  int px0 = pairIdx, px1 = pairIdx + PP;

  float acc0[OPG], acc1[OPG];
#pragma unroll
  for (int o = 0; o < OPG; ++o) { float bb = bias[obase + o]; acc0[o] = bb; acc1[o] = bb; }

  for (int k = 0; k < 9; ++k) {
    // issue next-k weight loads early (overlap with compute below)
    if (k < 8) {
      const float4* src = (const float4*)(wT + (size_t)(k + 1) * CIN * COUT);
#pragma unroll
      for (int j = 0; j < NPRE; ++j) {
        int t = threadIdx.x + j * 256;
        if (t < WN4) wpre[j] = src[t];
      }
    }
#pragma unroll
    for (int c4 = 0; c4 < QT; ++c4) {
      float4 p0 = *(const float4*)&patch[px0 * PSTR + k * CIN + 4 * c4];
      float4 p1 = *(const float4*)&patch[px1 * PSTR + k * CIN + 4 * c4];
      const float* pv0 = &p0.x;
      const float* pv1 = &p1.x;
#pragma unroll
      for (int cc = 0; cc < 4; ++cc) {
        float4 wv = *(const float4*)&wsk[(4 * c4 + cc) * COUT + obase];
        acc0[0] = fmaf(wv.x, pv0[cc], acc0[0]);
        acc0[1] = fmaf(wv.y, pv0[cc], acc0[1]);
        acc0[2] = fmaf(wv.z, pv0[cc], acc0[2]);
        acc0[3] = fmaf(wv.w, pv0[cc], acc0[3]);
        acc1[0] = fmaf(wv.x, pv1[cc], acc1[0]);
        acc1[1] = fmaf(wv.y, pv1[cc], acc1[1]);
        acc1[2] = fmaf(wv.z, pv1[cc], acc1[2]);
        acc1[3] = fmaf(wv.w, pv1[cc], acc1[3]);
      }
    }
    if (k < 8) {
      __syncthreads();      // all reads of wsk(k) done
#pragma unroll
      for (int j = 0; j < NPRE; ++j) {
        int t = threadIdx.x + j * 256;
        if (t < WN4) ((float4*)wsk)[t] = wpre[j];
      }
      __syncthreads();      // wsk = weights(k+1)
    }
  }

  float* ob = out + ((size_t)b * COUT + obase) * HW + p0_in_b;
#pragma unroll
  for (int o = 0; o < OPG; ++o) {
    ob[(size_t)o * HW + px0] = fmaxf(acc0[o], 0.f);
    ob[(size_t)o * HW + px1] = fmaxf(acc1[o], 0.f);
  }
}

// ---- Adaptive avg pool 24->3 (8x8 bins) + fc(576->10), NCHW input.
__global__ void poolfc_kernel(const float* __restrict__ h,   // [B,64,24,24]
                              const float* __restrict__ wfc, // [10,576]
                              const float* __restrict__ bfc, // [10]
                              float* __restrict__ out) {     // [B,10]
  __shared__ float feat[576];
  int b = blockIdx.x;
  int f = threadIdx.x; // 576 threads
  int c = f / 9, ij = f % 9, i = ij / 3, j = ij % 3;
  const float* p = h + ((size_t)(b * 64 + c) * 24 + i * 8) * 24 + j * 8;
  float s = 0.f;
#pragma unroll
  for (int r = 0; r < 8; ++r)
#pragma unroll
    for (int q = 0; q < 8; ++q)
      s += p[r * 24 + q];
  feat[f] = s * (1.f / 64.f);
  __syncthreads();
  if (f < 10) {
    float acc = bfc[f];
    const float* wp = wfc + f * 576;
    for (int t = 0; t < 576; ++t) acc = fmaf(wp[t], feat[t], acc);
    out[b * 10 + f] = acc;
  }
}

extern "C" void kernel_launch(void* const* d_in, const int* in_sizes, int n_in,
                              void* d_out, int out_size, void* d_ws, size_t ws_size,
                              hipStream_t stream) {
  const float* x      = (const float*)d_in[0];
  const float* w_off1 = (const float*)d_in[1];
  const float* b_off1 = (const float*)d_in[2];
  const float* w1     = (const float*)d_in[3];
  const float* b1     = (const float*)d_in[4];
  const float* w_off2 = (const float*)d_in[5];
  const float* b_off2 = (const float*)d_in[6];
  const float* w2     = (const float*)d_in[7];
  const float* b2     = (const float*)d_in[8];
  const float* w_off3 = (const float*)d_in[9];
  const float* b_off3 = (const float*)d_in[10];
  const float* w3     = (const float*)d_in[11];
  const float* b3     = (const float*)d_in[12];
  const float* w_fc   = (const float*)d_in[13];
  const float* b_fc   = (const float*)d_in[14];
  float* out = (float*)d_out;

  char* ws = (char*)d_ws;
  float* A   = (float*)(ws);
  float* Cp  = (float*)(ws + 18874368);
  float* Bp  = (float*)(ws + 37748736);
  float* wT2 = (float*)(ws + 47185920);
  float* wT3 = (float*)(ws + 47185920 + 9 * 16 * 32 * 4);

  const int thr = 256;

  // Weight transposes (independent, run first)
  wtrans<16, 32><<<(9 * 16 * 32 + 255) / 256, thr, 0, stream>>>(w2, wT2);
  wtrans<32, 64><<<(9 * 32 * 64 + 255) / 256, thr, 0, stream>>>(w3, wT3);

  // Layer 1: fused offset+deform+relu -> A [64,16,96,96] NCHW (2 px/thread)
  deform1_fused<<<64 * 96 * 96 / 2 / thr, thr, 0, stream>>>(x, w_off1, b_off1, w1, b1, A);
  // pool -> Bp [64,48,48,16] NHWC
  {
    int total = 64 * 48 * 48 * 4;
    pool_nchw_to_nhwc<16, 96><<<(total + thr - 1) / thr, thr, 0, stream>>>(A, Bp);
  }

  // Layer 2: offset conv -> Cp [64,48,48,20] padded NHWC
  conv3x3_off<16, 18, 1><<<dim3(576, 1), thr, 0, stream>>>(Bp, w_off2, b_off2, Cp, 64, 48, 48);
  // deform + relu -> A [64,32,48,48] NCHW  (PX=64: 2304 blocks, 44KB LDS)
  deform_patch<16, 32, 48, 64><<<64 * 48 * 48 / 64, thr, 0, stream>>>(Bp, Cp, wT2, b2, A);
  // pool -> Bp [64,24,24,32] NHWC
  {
    int total = 64 * 24 * 24 * 8;
    pool_nchw_to_nhwc<32, 48><<<(total + thr - 1) / thr, thr, 0, stream>>>(A, Bp);
  }

  // Layer 3: offset conv -> Cp [64,24,24,20] padded NHWC
  conv3x3_off<32, 18, 3><<<dim3(144, 3), thr, 0, stream>>>(Bp, w_off3, b_off3, Cp, 64, 24, 24);
  // deform + relu -> A [64,64,24,24] NCHW  (PX=32: 1152 blocks, 47KB LDS)
  deform_patch<32, 64, 24, 32><<<64 * 24 * 24 / 32, thr, 0, stream>>>(Bp, Cp, wT3, b3, A);

  // avgpool(3x3) + fc -> out [64,10]
  poolfc_kernel<<<64, 576, 0, stream>>>(A, w_fc, b_fc, out);
}

// Round 14
// 756.473 us; speedup vs baseline: 1.4237x; 1.4237x over previous
//
#include <hip/hip_runtime.h>
#include <math.h>

// ---------------------------------------------------------------------------
// PermutedNetwork, R14 = R12 (175.7us, best) + async-DMA weight staging in
// the L2 deform. R13 lesson (4th spill disaster): register prefetch arrays
// spanning the unrolled FMA body always spill. global_load_lds moves the
// k+1 weight slice global->LDS with NO register data path; the k-loop's
// __syncthreads (implicit vmcnt(0) drain) completes it after compute.
// One barrier/k (was 2), staging latency hidden. L3 deform: R12 verbatim
// (double-buffer there would cost a block of occupancy).
// ---------------------------------------------------------------------------

typedef const void GV __attribute__((address_space(1)));
typedef void LV __attribute__((address_space(3)));

// ---- Weight transpose: w[o][c][k] -> wT[k][c][o] (run once, tiny).
template <int CIN, int COUT>
__global__ void wtrans(const float* __restrict__ w, float* __restrict__ wT) {
  int t = blockIdx.x * 256 + threadIdx.x;
  if (t >= 9 * CIN * COUT) return;
  int k = t / (CIN * COUT);
  int r = t % (CIN * COUT);
  int c = r / COUT;
  int o = r % COUT;
  wT[t] = w[(o * CIN + c) * 9 + k];
}

// ---- Layer 1: fused offset-conv + deform + relu, CIN=1. 2 pixels/thread.
__global__ void deform1_fused(const float* __restrict__ x,    // [64,96,96]
                              const float* __restrict__ woff, // [18,1,3,3]
                              const float* __restrict__ boff, // [18]
                              const float* __restrict__ w1,   // [16,1,3,3]
                              const float* __restrict__ b1,   // [16]
                              float* __restrict__ out) {      // [64,16,96,96]
  const int H = 96, W = 96, HW = H * W;
  __shared__ float wos[9 * 18];
  __shared__ __align__(16) float ws1[9 * 16];
  for (int t = threadIdx.x; t < 9 * 18; t += 256) { int k = t / 18, tc = t % 18; wos[t] = woff[tc * 9 + k]; }
  for (int t = threadIdx.x; t < 9 * 16; t += 256) { int k = t / 16, o = t % 16; ws1[t] = w1[o * 9 + k]; }
  __syncthreads();

  int gid = blockIdx.x * 256 + threadIdx.x;
  int p2 = gid % (HW / 2);
  int b  = gid / (HW / 2);
  int xi0 = (2 * p2) % W, yi = (2 * p2) / W;
  const float* xb = x + (size_t)b * HW;

  float v[3][4];
#pragma unroll
  for (int r = 0; r < 3; ++r) {
    int yy = yi + r - 1;
    float my = (yy >= 0 && yy < H) ? 1.f : 0.f;
    int cy = min(max(yy, 0), H - 1);
#pragma unroll
    for (int c = 0; c < 4; ++c) {
      int xx = xi0 + c - 1;
      float mx = (xx >= 0 && xx < W) ? 1.f : 0.f;
      int cx = min(max(xx, 0), W - 1);
      v[r][c] = xb[cy * W + cx] * (my * mx);
    }
  }

  float off0[18], off1[18];
#pragma unroll
  for (int tc = 0; tc < 18; ++tc) { float bb = boff[tc]; off0[tc] = bb; off1[tc] = bb; }
#pragma unroll
  for (int r = 0; r < 3; ++r)
#pragma unroll
    for (int c = 0; c < 3; ++c) {
      float t0 = v[r][c], t1 = v[r][c + 1];
      const float2* wv = (const float2*)&wos[(r * 3 + c) * 18];
#pragma unroll
      for (int tt = 0; tt < 9; ++tt) {
        float2 ww = wv[tt];
        off0[2 * tt]     = fmaf(ww.x, t0, off0[2 * tt]);
        off0[2 * tt + 1] = fmaf(ww.y, t0, off0[2 * tt + 1]);
        off1[2 * tt]     = fmaf(ww.x, t1, off1[2 * tt]);
        off1[2 * tt + 1] = fmaf(ww.y, t1, off1[2 * tt + 1]);
      }
    }

  float acc0[16], acc1[16];
#pragma unroll
  for (int o = 0; o < 16; ++o) { float bb = b1[o]; acc0[o] = bb; acc1[o] = bb; }

#pragma unroll
  for (int k = 0; k < 9; ++k) {
    int dky = k / 3 - 1, dkx = k % 3 - 1;
    float val0, val1;
    {
      float py = (float)(yi + dky) + off0[2 * k];
      float px = (float)(xi0 + dkx) + off0[2 * k + 1];
      float y0f = floorf(py), x0f = floorf(px);
      float fy = py - y0f, fx = px - x0f;
      int y0 = (int)y0f, x0 = (int)x0f, y1 = y0 + 1, x1 = x0 + 1;
      float vy0 = (y0 >= 0 && y0 < H) ? 1.f : 0.f;
      float vy1 = (y1 >= 0 && y1 < H) ? 1.f : 0.f;
      float vx0 = (x0 >= 0 && x0 < W) ? 1.f : 0.f;
      float vx1 = (x1 >= 0 && x1 < W) ? 1.f : 0.f;
      float w00 = (1.f - fy) * (1.f - fx) * vy0 * vx0;
      float w01 = (1.f - fy) * fx * vy0 * vx1;
      float w10 = fy * (1.f - fx) * vy1 * vx0;
      float w11 = fy * fx * vy1 * vx1;
      int cy0 = min(max(y0, 0), H - 1), cy1 = min(max(y1, 0), H - 1);
      int cx0 = min(max(x0, 0), W - 1), cx1 = min(max(x1, 0), W - 1);
      float a = xb[cy0 * W + cx0], bb = xb[cy0 * W + cx1];
      float c = xb[cy1 * W + cx0], d = xb[cy1 * W + cx1];
      val0 = w00 * a + w01 * bb + w10 * c + w11 * d;
    }
    {
      float py = (float)(yi + dky) + off1[2 * k];
      float px = (float)(xi0 + 1 + dkx) + off1[2 * k + 1];
      float y0f = floorf(py), x0f = floorf(px);
      float fy = py - y0f, fx = px - x0f;
      int y0 = (int)y0f, x0 = (int)x0f, y1 = y0 + 1, x1 = x0 + 1;
      float vy0 = (y0 >= 0 && y0 < H) ? 1.f : 0.f;
      float vy1 = (y1 >= 0 && y1 < H) ? 1.f : 0.f;
      float vx0 = (x0 >= 0 && x0 < W) ? 1.f : 0.f;
      float vx1 = (x1 >= 0 && x1 < W) ? 1.f : 0.f;
      float w00 = (1.f - fy) * (1.f - fx) * vy0 * vx0;
      float w01 = (1.f - fy) * fx * vy0 * vx1;
      float w10 = fy * (1.f - fx) * vy1 * vx0;
      float w11 = fy * fx * vy1 * vx1;
      int cy0 = min(max(y0, 0), H - 1), cy1 = min(max(y1, 0), H - 1);
      int cx0 = min(max(x0, 0), W - 1), cx1 = min(max(x1, 0), W - 1);
      float a = xb[cy0 * W + cx0], bb = xb[cy0 * W + cx1];
      float c = xb[cy1 * W + cx0], d = xb[cy1 * W + cx1];
      val1 = w00 * a + w01 * bb + w10 * c + w11 * d;
    }
    const float4* wv = (const float4*)&ws1[k * 16];
#pragma unroll
    for (int q = 0; q < 4; ++q) {
      float4 w4 = wv[q];
      acc0[4 * q + 0] = fmaf(w4.x, val0, acc0[4 * q + 0]);
      acc0[4 * q + 1] = fmaf(w4.y, val0, acc0[4 * q + 1]);
      acc0[4 * q + 2] = fmaf(w4.z, val0, acc0[4 * q + 2]);
      acc0[4 * q + 3] = fmaf(w4.w, val0, acc0[4 * q + 3]);
      acc1[4 * q + 0] = fmaf(w4.x, val1, acc1[4 * q + 0]);
      acc1[4 * q + 1] = fmaf(w4.y, val1, acc1[4 * q + 1]);
      acc1[4 * q + 2] = fmaf(w4.z, val1, acc1[4 * q + 2]);
      acc1[4 * q + 3] = fmaf(w4.w, val1, acc1[4 * q + 3]);
    }
  }

  float* op = out + (size_t)b * 16 * HW + (size_t)yi * W + xi0;
#pragma unroll
  for (int o = 0; o < 16; ++o) {
    float2 r = make_float2(fmaxf(acc0[o], 0.f), fmaxf(acc1[o], 0.f));
    *(float2*)(op + (size_t)o * HW) = r;
  }
}

// ---- 2x2 maxpool, NCHW in -> NHWC out.
template <int C, int HI>
__global__ void pool_nchw_to_nhwc(const float* __restrict__ in,  // [B,C,HI,HI]
                                  float* __restrict__ out) {     // [B,HO,HO,C]
  const int HO = HI / 2, C4 = C / 4;
  int gid = blockIdx.x * blockDim.x + threadIdx.x;
  if (gid >= 64 * HO * HO * C4) return;
  int c4 = gid % C4;
  int t = gid / C4;
  int x = t % HO; t /= HO;
  int y = t % HO;
  int b = t / HO;
  float4 r;
  float* rp = &r.x;
#pragma unroll
  for (int cc = 0; cc < 4; ++cc) {
    int c = c4 * 4 + cc;
    const float* p = in + ((size_t)(b * C + c) * HI + 2 * y) * HI + 2 * x;
    rp[cc] = fmaxf(fmaxf(p[0], p[1]), fmaxf(p[HI], p[HI + 1]));
  }
  *(float4*)(out + (((size_t)b * HO + y) * HO + x) * C + c4 * 4) = r;
}

// ---- 3x3 conv for offsets: NHWC in, PADDED NHWC out [B,H,W,20].
template <int CIN, int COUT, int NSPLIT>
__global__ __launch_bounds__(256, 4)
void conv3x3_off(const float* __restrict__ in,  // [B,H,W,CIN]
                 const float* __restrict__ w,   // [COUT,CIN,3,3]
                 const float* __restrict__ bias,
                 float* __restrict__ out,       // [B,H,W,20]
                 int B, int H, int W) {
  constexpr int OC = COUT / NSPLIT;
  __shared__ float ws[9 * CIN * OC];
  int obase = blockIdx.y * OC;
  for (int t = threadIdx.x; t < 9 * CIN * OC; t += 256) {
    int k = t / (CIN * OC); int r = t % (CIN * OC);
    int c = r / OC; int o = r % OC;
    ws[t] = w[((obase + o) * CIN + c) * 9 + k];
  }
  __syncthreads();

  int gid = blockIdx.x * 256 + threadIdx.x;
  if (gid >= B * H * W) return;
  int x = gid % W; int t0 = gid / W; int y = t0 % H; int b = t0 / H;
  int HW = H * W;
  const float* inb = in + (size_t)b * HW * CIN;

  float acc[OC];
#pragma unroll
  for (int o = 0; o < OC; ++o) acc[o] = bias[obase + o];

#pragma unroll
  for (int ky = 0; ky < 3; ++ky) {
    int yy = y + ky - 1;
    if (yy < 0 || yy >= H) continue;
#pragma unroll
    for (int kx = 0; kx < 3; ++kx) {
      int xx = x + kx - 1;
      if (xx < 0 || xx >= W) continue;
      const float4* p4 = (const float4*)(inb + ((size_t)yy * W + xx) * CIN);
      int k = ky * 3 + kx;
#pragma unroll
      for (int c4 = 0; c4 < CIN / 4; ++c4) {
        float4 p = p4[c4];
        const float* pv = &p.x;
#pragma unroll
        for (int cc = 0; cc < 4; ++cc) {
          const float* wrow = &ws[(k * CIN + 4 * c4 + cc) * OC];
#pragma unroll
          for (int o = 0; o < OC; ++o) acc[o] = fmaf(wrow[o], pv[cc], acc[o]);
        }
      }
    }
  }

  float* op = out + (size_t)gid * 20 + obase;
#pragma unroll
  for (int o = 0; o < OC; ++o) op[o] = acc[o];
}

// ---- L2 deform: two-phase patch-LDS + ASYNC double-buffered weight staging.
// global_load_lds: per-lane global addr, wave-uniform LDS base (+lane*16B).
template <int CIN, int COUT, int HW_, int PX>
__global__ void deform_patch_async(const float* __restrict__ in,     // [B,H,W,CIN]
                                   const float* __restrict__ off_in, // [B*HW,20]
                                   const float* __restrict__ wT,     // [9][CIN][COUT]
                                   const float* __restrict__ bias,
                                   float* __restrict__ out) {        // [B,COUT,H,W]
  constexpr int H = HW_, W = HW_, HW = H * W;
  constexpr int QT = CIN / 4;
  static_assert(PX * QT == 256, "block mapping");
  constexpr int PSTR = 9 * CIN + 4;
  constexpr int PP = PX / 2;
  constexpr int OG = 256 / PP;
  constexpr int OPG = COUT / OG;
  static_assert(OPG == 4, "phase2 mapping");
  constexpr int WN4 = CIN * COUT / 4;     // weight float4s per k (128)
  constexpr int LW  = WN4 / 64;           // waves that issue loads (2)

  __shared__ __align__(16) float offs[PX * 20];
  __shared__ __align__(16) float patch[PX * PSTR];
  __shared__ __align__(16) float wsk[2][CIN * COUT];

  const int pixbase = blockIdx.x * PX;
  const int b = pixbase / HW;
  const int p0_in_b = pixbase - b * HW;
  const float* inb = in + (size_t)b * HW * CIN;

  const int wv = threadIdx.x >> 6;
  const int lane = threadIdx.x & 63;

  // issue async load of k=0 weights (completes under phase 1's end barrier)
  if (wv < LW) {
    const float* gsrc = wT + (size_t)(wv * 64 + lane) * 4;
    __builtin_amdgcn_global_load_lds((GV*)gsrc, (LV*)&wsk[0][wv * 256], 16, 0, 0);
  }

  // stage offsets (contiguous)
  {
    const float4* src = (const float4*)(off_in + (size_t)pixbase * 20);
    for (int t = threadIdx.x; t < PX * 20 / 4; t += 256)
      ((float4*)offs)[t] = src[t];
  }
  __syncthreads();

  // ---- phase 1: build patches (lane map: px = tid/QT, q = tid%QT)
  {
    int px = threadIdx.x / QT;
    int q  = threadIdx.x % QT;
    int pib = p0_in_b + px;
    int yi = pib / W, xi = pib % W;
#pragma unroll
    for (int k = 0; k < 9; ++k) {
      float py = (float)(yi + k / 3 - 1) + offs[px * 20 + 2 * k];
      float pxx = (float)(xi + k % 3 - 1) + offs[px * 20 + 2 * k + 1];
      float y0f = floorf(py), x0f = floorf(pxx);
      float fy = py - y0f, fx = pxx - x0f;
      int y0 = (int)y0f, x0 = (int)x0f, y1 = y0 + 1, x1 = x0 + 1;
      float vy0 = (y0 >= 0 && y0 < H) ? 1.f : 0.f;
      float vy1 = (y1 >= 0 && y1 < H) ? 1.f : 0.f;
      float vx0 = (x0 >= 0 && x0 < W) ? 1.f : 0.f;
      float vx1 = (x1 >= 0 && x1 < W) ? 1.f : 0.f;
      float w00 = (1.f - fy) * (1.f - fx) * vy0 * vx0;
      float w01 = (1.f - fy) * fx * vy0 * vx1;
      float w10 = fy * (1.f - fx) * vy1 * vx0;
      float w11 = fy * fx * vy1 * vx1;
      int cy0 = min(max(y0, 0), H - 1), cy1 = min(max(y1, 0), H - 1);
      int cx0 = min(max(x0, 0), W - 1), cx1 = min(max(x1, 0), W - 1);
      float4 A  = *(const float4*)(inb + ((size_t)cy0 * W + cx0) * CIN + 4 * q);
      float4 Bv = *(const float4*)(inb + ((size_t)cy0 * W + cx1) * CIN + 4 * q);
      float4 Cv = *(const float4*)(inb + ((size_t)cy1 * W + cx0) * CIN + 4 * q);
      float4 Dv = *(const float4*)(inb + ((size_t)cy1 * W + cx1) * CIN + 4 * q);
      float4 val;
      val.x = w00 * A.x + w01 * Bv.x + w10 * Cv.x + w11 * Dv.x;
      val.y = w00 * A.y + w01 * Bv.y + w10 * Cv.y + w11 * Dv.y;
      val.z = w00 * A.z + w01 * Bv.z + w10 * Cv.z + w11 * Dv.z;
      val.w = w00 * A.w + w01 * Bv.w + w10 * Cv.w + w11 * Dv.w;
      *(float4*)&patch[px * PSTR + k * CIN + 4 * q] = val;
    }
  }
  __syncthreads();   // patches + k=0 weights both complete (implicit vmcnt(0))

  // ---- phase 2: GEMM from LDS, async prefetch of k+1 weights
  int pairIdx = threadIdx.x % PP;
  int og = threadIdx.x / PP;
  int obase = og * OPG;
  int px0 = pairIdx, px1 = pairIdx + PP;

  float acc0[OPG], acc1[OPG];
#pragma unroll
  for (int o = 0; o < OPG; ++o) { float bb = bias[obase + o]; acc0[o] = bb; acc1[o] = bb; }

  for (int k = 0; k < 9; ++k) {
    if (k < 8 && wv < LW) {
      const float* gsrc = wT + (size_t)(k + 1) * CIN * COUT + (size_t)(wv * 64 + lane) * 4;
      __builtin_amdgcn_global_load_lds((GV*)gsrc, (LV*)&wsk[(k + 1) & 1][wv * 256], 16, 0, 0);
    }
    const float* wb = wsk[k & 1];
#pragma unroll
    for (int c4 = 0; c4 < QT; ++c4) {
      float4 p0 = *(const float4*)&patch[px0 * PSTR + k * CIN + 4 * c4];
      float4 p1 = *(const float4*)&patch[px1 * PSTR + k * CIN + 4 * c4];
      const float* pv0 = &p0.x;
      const float* pv1 = &p1.x;
#pragma unroll
      for (int cc = 0; cc < 4; ++cc) {
        float4 wv4 = *(const float4*)&wb[(4 * c4 + cc) * COUT + obase];
        acc0[0] = fmaf(wv4.x, pv0[cc], acc0[0]);
        acc0[1] = fmaf(wv4.y, pv0[cc], acc0[1]);
        acc0[2] = fmaf(wv4.z, pv0[cc], acc0[2]);
        acc0[3] = fmaf(wv4.w, pv0[cc], acc0[3]);
        acc1[0] = fmaf(wv4.x, pv1[cc], acc1[0]);
        acc1[1] = fmaf(wv4.y, pv1[cc], acc1[1]);
        acc1[2] = fmaf(wv4.z, pv1[cc], acc1[2]);
        acc1[3] = fmaf(wv4.w, pv1[cc], acc1[3]);
      }
    }
    if (k < 8) __syncthreads();  // implicit vmcnt(0): k+1 weights landed;
                                 // also fences reads of wsk[k&1] before reuse
  }

  float* ob = out + ((size_t)b * COUT + obase) * HW + p0_in_b;
#pragma unroll
  for (int o = 0; o < OPG; ++o) {
    ob[(size_t)o * HW + px0] = fmaxf(acc0[o], 0.f);
    ob[(size_t)o * HW + px1] = fmaxf(acc1[o], 0.f);
  }
}

// ---- L3 deform: R12-verbatim two-phase patch-LDS (sync per-k staging).
template <int CIN, int COUT, int HW_, int PX>
__global__ void deform_patch(const float* __restrict__ in,     // [B,H,W,CIN]
                             const float* __restrict__ off_in, // [B*HW,20]
                             const float* __restrict__ wT,     // [9][CIN][COUT]
                             const float* __restrict__ bias,
                             float* __restrict__ out) {        // [B,COUT,H,W]
  constexpr int H = HW_, W = HW_, HW = H * W;
  constexpr int QT = CIN / 4;
  static_assert(PX * QT == 256, "block mapping");
  constexpr int PSTR = 9 * CIN + 4;
  constexpr int PP = PX / 2;
  constexpr int OG = 256 / PP;
  constexpr int OPG = COUT / OG;
  static_assert(OPG == 4, "phase2 mapping");

  __shared__ __align__(16) float offs[PX * 20];
  __shared__ __align__(16) float patch[PX * PSTR];
  __shared__ __align__(16) float wsk[CIN * COUT];

  const int pixbase = blockIdx.x * PX;
  const int b = pixbase / HW;
  const int p0_in_b = pixbase - b * HW;
  const float* inb = in + (size_t)b * HW * CIN;

  {
    const float4* src = (const float4*)(off_in + (size_t)pixbase * 20);
    for (int t = threadIdx.x; t < PX * 20 / 4; t += 256)
      ((float4*)offs)[t] = src[t];
  }
  __syncthreads();

  {
    int px = threadIdx.x / QT;
    int q  = threadIdx.x % QT;
    int pib = p0_in_b + px;
    int yi = pib / W, xi = pib % W;
#pragma unroll
    for (int k = 0; k < 9; ++k) {
      float py = (float)(yi + k / 3 - 1) + offs[px * 20 + 2 * k];
      float pxx = (float)(xi + k % 3 - 1) + offs[px * 20 + 2 * k + 1];
      float y0f = floorf(py), x0f = floorf(pxx);
      float fy = py - y0f, fx = pxx - x0f;
      int y0 = (int)y0f, x0 = (int)x0f, y1 = y0 + 1, x1 = x0 + 1;
      float vy0 = (y0 >= 0 && y0 < H) ? 1.f : 0.f;
      float vy1 = (y1 >= 0 && y1 < H) ? 1.f : 0.f;
      float vx0 = (x0 >= 0 && x0 < W) ? 1.f : 0.f;
      float vx1 = (x1 >= 0 && x1 < W) ? 1.f : 0.f;
      float w00 = (1.f - fy) * (1.f - fx) * vy0 * vx0;
      float w01 = (1.f - fy) * fx * vy0 * vx1;
      float w10 = fy * (1.f - fx) * vy1 * vx0;
      float w11 = fy * fx * vy1 * vx1;
      int cy0 = min(max(y0, 0), H - 1), cy1 = min(max(y1, 0), H - 1);
      int cx0 = min(max(x0, 0), W - 1), cx1 = min(max(x1, 0), W - 1);
      float4 A  = *(const float4*)(inb + ((size_t)cy0 * W + cx0) * CIN + 4 * q);
      float4 Bv = *(const float4*)(inb + ((size_t)cy0 * W + cx1) * CIN + 4 * q);
      float4 Cv = *(const float4*)(inb + ((size_t)cy1 * W + cx0) * CIN + 4 * q);
      float4 Dv = *(const float4*)(inb + ((size_t)cy1 * W + cx1) * CIN + 4 * q);
      float4 val;
      val.x = w00 * A.x + w01 * Bv.x + w10 * Cv.x + w11 * Dv.x;
      val.y = w00 * A.y + w01 * Bv.y + w10 * Cv.y + w11 * Dv.y;
      val.z = w00 * A.z + w01 * Bv.z + w10 * Cv.z + w11 * Dv.z;
      val.w = w00 * A.w + w01 * Bv.w + w10 * Cv.w + w11 * Dv.w;
      *(float4*)&patch[px * PSTR + k * CIN + 4 * q] = val;
    }
  }

  int pairIdx = threadIdx.x % PP;
  int og = threadIdx.x / PP;
  int obase = og * OPG;
  int px0 = pairIdx, px1 = pairIdx + PP;

  float acc0[OPG], acc1[OPG];
#pragma unroll
  for (int o = 0; o < OPG; ++o) { float bb = bias[obase + o]; acc0[o] = bb; acc1[o] = bb; }

  for (int k = 0; k < 9; ++k) {
    __syncthreads();
    {
      const float4* src = (const float4*)(wT + (size_t)k * CIN * COUT);
      for (int t = threadIdx.x; t < CIN * COUT / 4; t += 256)
        ((float4*)wsk)[t] = src[t];
    }
    __syncthreads();
#pragma unroll
    for (int c4 = 0; c4 < QT; ++c4) {
      float4 p0 = *(const float4*)&patch[px0 * PSTR + k * CIN + 4 * c4];
      float4 p1 = *(const float4*)&patch[px1 * PSTR + k * CIN + 4 * c4];
      const float* pv0 = &p0.x;
      const float* pv1 = &p1.x;
#pragma unroll
      for (int cc = 0; cc < 4; ++cc) {
        float4 wv = *(const float4*)&wsk[(4 * c4 + cc) * COUT + obase];
        acc0[0] = fmaf(wv.x, pv0[cc], acc0[0]);
        acc0[1] = fmaf(wv.y, pv0[cc], acc0[1]);
        acc0[2] = fmaf(wv.z, pv0[cc], acc0[2]);
        acc0[3] = fmaf(wv.w, pv0[cc], acc0[3]);
        acc1[0] = fmaf(wv.x, pv1[cc], acc1[0]);
        acc1[1] = fmaf(wv.y, pv1[cc], acc1[1]);
        acc1[2] = fmaf(wv.z, pv1[cc], acc1[2]);
        acc1[3] = fmaf(wv.w, pv1[cc], acc1[3]);
      }
    }
  }

  float* ob = out + ((size_t)b * COUT + obase) * HW + p0_in_b;
#pragma unroll
  for (int o = 0; o < OPG; ++o) {
    ob[(size_t)o * HW + px0] = fmaxf(acc0[o], 0.f);
    ob[(size_t)o * HW + px1] = fmaxf(acc1[o], 0.f);
  }
}

// ---- Adaptive avg pool 24->3 (8x8 bins) + fc(576->10), NCHW input.
__global__ void poolfc_kernel(const float* __restrict__ h,   // [B,64,24,24]
                              const float* __restrict__ wfc, // [10,576]
                              const float* __restrict__ bfc, // [10]
                              float* __restrict__ out) {     // [B,10]
  __shared__ float feat[576];
  int b = blockIdx.x;
  int f = threadIdx.x; // 576 threads
  int c = f / 9, ij = f % 9, i = ij / 3, j = ij % 3;
  const float* p = h + ((size_t)(b * 64 + c) * 24 + i * 8) * 24 + j * 8;
  float s = 0.f;
#pragma unroll
  for (int r = 0; r < 8; ++r)
#pragma unroll
    for (int q = 0; q < 8; ++q)
      s += p[r * 24 + q];
  feat[f] = s * (1.f / 64.f);
  __syncthreads();
  if (f < 10) {
    float acc = bfc[f];
    const float* wp = wfc + f * 576;
    for (int t = 0; t < 576; ++t) acc = fmaf(wp[t], feat[t], acc);
    out[b * 10 + f] = acc;
  }
}

extern "C" void kernel_launch(void* const* d_in, const int* in_sizes, int n_in,
                              void* d_out, int out_size, void* d_ws, size_t ws_size,
                              hipStream_t stream) {
  const float* x      = (const float*)d_in[0];
  const float* w_off1 = (const float*)d_in[1];
  const float* b_off1 = (const float*)d_in[2];
  const float* w1     = (const float*)d_in[3];
  const float* b1     = (const float*)d_in[4];
  const float* w_off2 = (const float*)d_in[5];
  const float* b_off2 = (const float*)d_in[6];
  const float* w2     = (const float*)d_in[7];
  const float* b2     = (const float*)d_in[8];
  const float* w_off3 = (const float*)d_in[9];
  const float* b_off3 = (const float*)d_in[10];
  const float* w3     = (const float*)d_in[11];
  const float* b3     = (const float*)d_in[12];
  const float* w_fc   = (const float*)d_in[13];
  const float* b_fc   = (const float*)d_in[14];
  float* out = (float*)d_out;

  char* ws = (char*)d_ws;
  float* A   = (float*)(ws);
  float* Cp  = (float*)(ws + 18874368);
  float* Bp  = (float*)(ws + 37748736);
  float* wT2 = (float*)(ws + 47185920);
  float* wT3 = (float*)(ws + 47185920 + 9 * 16 * 32 * 4);

  const int thr = 256;

  // Weight transposes (independent, run first)
  wtrans<16, 32><<<(9 * 16 * 32 + 255) / 256, thr, 0, stream>>>(w2, wT2);
  wtrans<32, 64><<<(9 * 32 * 64 + 255) / 256, thr, 0, stream>>>(w3, wT3);

  // Layer 1: fused offset+deform+relu -> A [64,16,96,96] NCHW (2 px/thread)
  deform1_fused<<<64 * 96 * 96 / 2 / thr, thr, 0, stream>>>(x, w_off1, b_off1, w1, b1, A);
  // pool -> Bp [64,48,48,16] NHWC
  {
    int total = 64 * 48 * 48 * 4;
    pool_nchw_to_nhwc<16, 96><<<(total + thr - 1) / thr, thr, 0, stream>>>(A, Bp);
  }

  // Layer 2: offset conv -> Cp [64,48,48,20] padded NHWC
  conv3x3_off<16, 18, 1><<<dim3(576, 1), thr, 0, stream>>>(Bp, w_off2, b_off2, Cp, 64, 48, 48);
  // deform + relu -> A [64,32,48,48] NCHW  (PX=64: 2304 blocks, 46KB LDS)
  deform_patch_async<16, 32, 48, 64><<<64 * 48 * 48 / 64, thr, 0, stream>>>(Bp, Cp, wT2, b2, A);
  // pool -> Bp [64,24,24,32] NHWC
  {
    int total = 64 * 24 * 24 * 8;
    pool_nchw_to_nhwc<32, 48><<<(total + thr - 1) / thr, thr, 0, stream>>>(A, Bp);
  }

  // Layer 3: offset conv -> Cp [64,24,24,20] padded NHWC
  conv3x3_off<32, 18, 3><<<dim3(144, 3), thr, 0, stream>>>(Bp, w_off3, b_off3, Cp, 64, 24, 24);
  // deform + relu -> A [64,64,24,24] NCHW  (PX=32: 1152 blocks, 47KB LDS)
  deform_patch<32, 64, 24, 32><<<64 * 24 * 24 / 32, thr, 0, stream>>>(Bp, Cp, wT3, b3, A);

  // avgpool(3x3) + fc -> out [64,10]
  poolfc_kernel<<<64, 576, 0, stream>>>(A, w_fc, b_fc, out);
}

// Round 15
// 176.072 us; speedup vs baseline: 6.1166x; 4.2964x over previous
//
#include <hip/hip_runtime.h>
#include <math.h>

// ---------------------------------------------------------------------------
// PermutedNetwork, R15 = R12 verbatim (175.7us, best).
// R13 (register prefetch) and R14 (global_load_lds double-buffer) both
// triggered allocator pathologies (VGPR 64 cap -> GB-scale scratch traffic).
// Five spill disasters (R4/R5/R7/R13/R14) establish: for this unrolled-FMA
// kernel family, added latency-hiding state always loses. R12's plain
// two-phase patch-LDS structure (3 blk/CU, no prefetch) is the stable point.
// ---------------------------------------------------------------------------

// ---- Weight transpose: w[o][c][k] -> wT[k][c][o] (run once, tiny).
template <int CIN, int COUT>
__global__ void wtrans(const float* __restrict__ w, float* __restrict__ wT) {
  int t = blockIdx.x * 256 + threadIdx.x;
  if (t >= 9 * CIN * COUT) return;
  int k = t / (CIN * COUT);
  int r = t % (CIN * COUT);
  int c = r / COUT;
  int o = r % COUT;
  wT[t] = w[(o * CIN + c) * 9 + k];
}

// ---- Layer 1: fused offset-conv + deform + relu, CIN=1. 2 pixels/thread.
__global__ void deform1_fused(const float* __restrict__ x,    // [64,96,96]
                              const float* __restrict__ woff, // [18,1,3,3]
                              const float* __restrict__ boff, // [18]
                              const float* __restrict__ w1,   // [16,1,3,3]
                              const float* __restrict__ b1,   // [16]
                              float* __restrict__ out) {      // [64,16,96,96]
  const int H = 96, W = 96, HW = H * W;
  __shared__ float wos[9 * 18];
  __shared__ __align__(16) float ws1[9 * 16];
  for (int t = threadIdx.x; t < 9 * 18; t += 256) { int k = t / 18, tc = t % 18; wos[t] = woff[tc * 9 + k]; }
  for (int t = threadIdx.x; t < 9 * 16; t += 256) { int k = t / 16, o = t % 16; ws1[t] = w1[o * 9 + k]; }
  __syncthreads();

  int gid = blockIdx.x * 256 + threadIdx.x;
  int p2 = gid % (HW / 2);
  int b  = gid / (HW / 2);
  int xi0 = (2 * p2) % W, yi = (2 * p2) / W;
  const float* xb = x + (size_t)b * HW;

  float v[3][4];
#pragma unroll
  for (int r = 0; r < 3; ++r) {
    int yy = yi + r - 1;
    float my = (yy >= 0 && yy < H) ? 1.f : 0.f;
    int cy = min(max(yy, 0), H - 1);
#pragma unroll
    for (int c = 0; c < 4; ++c) {
      int xx = xi0 + c - 1;
      float mx = (xx >= 0 && xx < W) ? 1.f : 0.f;
      int cx = min(max(xx, 0), W - 1);
      v[r][c] = xb[cy * W + cx] * (my * mx);
    }
  }

  float off0[18], off1[18];
#pragma unroll
  for (int tc = 0; tc < 18; ++tc) { float bb = boff[tc]; off0[tc] = bb; off1[tc] = bb; }
#pragma unroll
  for (int r = 0; r < 3; ++r)
#pragma unroll
    for (int c = 0; c < 3; ++c) {
      float t0 = v[r][c], t1 = v[r][c + 1];
      const float2* wv = (const float2*)&wos[(r * 3 + c) * 18];
#pragma unroll
      for (int tt = 0; tt < 9; ++tt) {
        float2 ww = wv[tt];
        off0[2 * tt]     = fmaf(ww.x, t0, off0[2 * tt]);
        off0[2 * tt + 1] = fmaf(ww.y, t0, off0[2 * tt + 1]);
        off1[2 * tt]     = fmaf(ww.x, t1, off1[2 * tt]);
        off1[2 * tt + 1] = fmaf(ww.y, t1, off1[2 * tt + 1]);
      }
    }

  float acc0[16], acc1[16];
#pragma unroll
  for (int o = 0; o < 16; ++o) { float bb = b1[o]; acc0[o] = bb; acc1[o] = bb; }

#pragma unroll
  for (int k = 0; k < 9; ++k) {
    int dky = k / 3 - 1, dkx = k % 3 - 1;
    float val0, val1;
    {
      float py = (float)(yi + dky) + off0[2 * k];
      float px = (float)(xi0 + dkx) + off0[2 * k + 1];
      float y0f = floorf(py), x0f = floorf(px);
      float fy = py - y0f, fx = px - x0f;
      int y0 = (int)y0f, x0 = (int)x0f, y1 = y0 + 1, x1 = x0 + 1;
      float vy0 = (y0 >= 0 && y0 < H) ? 1.f : 0.f;
      float vy1 = (y1 >= 0 && y1 < H) ? 1.f : 0.f;
      float vx0 = (x0 >= 0 && x0 < W) ? 1.f : 0.f;
      float vx1 = (x1 >= 0 && x1 < W) ? 1.f : 0.f;
      float w00 = (1.f - fy) * (1.f - fx) * vy0 * vx0;
      float w01 = (1.f - fy) * fx * vy0 * vx1;
      float w10 = fy * (1.f - fx) * vy1 * vx0;
      float w11 = fy * fx * vy1 * vx1;
      int cy0 = min(max(y0, 0), H - 1), cy1 = min(max(y1, 0), H - 1);
      int cx0 = min(max(x0, 0), W - 1), cx1 = min(max(x1, 0), W - 1);
      float a = xb[cy0 * W + cx0], bb = xb[cy0 * W + cx1];
      float c = xb[cy1 * W + cx0], d = xb[cy1 * W + cx1];
      val0 = w00 * a + w01 * bb + w10 * c + w11 * d;
    }
    {
      float py = (float)(yi + dky) + off1[2 * k];
      float px = (float)(xi0 + 1 + dkx) + off1[2 * k + 1];
      float y0f = floorf(py), x0f = floorf(px);
      float fy = py - y0f, fx = px - x0f;
      int y0 = (int)y0f, x0 = (int)x0f, y1 = y0 + 1, x1 = x0 + 1;
      float vy0 = (y0 >= 0 && y0 < H) ? 1.f : 0.f;
      float vy1 = (y1 >= 0 && y1 < H) ? 1.f : 0.f;
      float vx0 = (x0 >= 0 && x0 < W) ? 1.f : 0.f;
      float vx1 = (x1 >= 0 && x1 < W) ? 1.f : 0.f;
      float w00 = (1.f - fy) * (1.f - fx) * vy0 * vx0;
      float w01 = (1.f - fy) * fx * vy0 * vx1;
      float w10 = fy * (1.f - fx) * vy1 * vx0;
      float w11 = fy * fx * vy1 * vx1;
      int cy0 = min(max(y0, 0), H - 1), cy1 = min(max(y1, 0), H - 1);
      int cx0 = min(max(x0, 0), W - 1), cx1 = min(max(x1, 0), W - 1);
      float a = xb[cy0 * W + cx0], bb = xb[cy0 * W + cx1];
      float c = xb[cy1 * W + cx0], d = xb[cy1 * W + cx1];
      val1 = w00 * a + w01 * bb + w10 * c + w11 * d;
    }
    const float4* wv = (const float4*)&ws1[k * 16];
#pragma unroll
    for (int q = 0; q < 4; ++q) {
      float4 w4 = wv[q];
      acc0[4 * q + 0] = fmaf(w4.x, val0, acc0[4 * q + 0]);
      acc0[4 * q + 1] = fmaf(w4.y, val0, acc0[4 * q + 1]);
      acc0[4 * q + 2] = fmaf(w4.z, val0, acc0[4 * q + 2]);
      acc0[4 * q + 3] = fmaf(w4.w, val0, acc0[4 * q + 3]);
      acc1[4 * q + 0] = fmaf(w4.x, val1, acc1[4 * q + 0]);
      acc1[4 * q + 1] = fmaf(w4.y, val1, acc1[4 * q + 1]);
      acc1[4 * q + 2] = fmaf(w4.z, val1, acc1[4 * q + 2]);
      acc1[4 * q + 3] = fmaf(w4.w, val1, acc1[4 * q + 3]);
    }
  }

  float* op = out + (size_t)b * 16 * HW + (size_t)yi * W + xi0;
#pragma unroll
  for (int o = 0; o < 16; ++o) {
    float2 r = make_float2(fmaxf(acc0[o], 0.f), fmaxf(acc1[o], 0.f));
    *(float2*)(op + (size_t)o * HW) = r;
  }
}

// ---- 2x2 maxpool, NCHW in -> NHWC out.
template <int C, int HI>
__global__ void pool_nchw_to_nhwc(const float* __restrict__ in,  // [B,C,HI,HI]
                                  float* __restrict__ out) {     // [B,HO,HO,C]
  const int HO = HI / 2, C4 = C / 4;
  int gid = blockIdx.x * blockDim.x + threadIdx.x;
  if (gid >= 64 * HO * HO * C4) return;
  int c4 = gid % C4;
  int t = gid / C4;
  int x = t % HO; t /= HO;
  int y = t % HO;
  int b = t / HO;
  float4 r;
  float* rp = &r.x;
#pragma unroll
  for (int cc = 0; cc < 4; ++cc) {
    int c = c4 * 4 + cc;
    const float* p = in + ((size_t)(b * C + c) * HI + 2 * y) * HI + 2 * x;
    rp[cc] = fmaxf(fmaxf(p[0], p[1]), fmaxf(p[HI], p[HI + 1]));
  }
  *(float4*)(out + (((size_t)b * HO + y) * HO + x) * C + c4 * 4) = r;
}

// ---- 3x3 conv for offsets: NHWC in, PADDED NHWC out [B,H,W,20].
template <int CIN, int COUT, int NSPLIT>
__global__ __launch_bounds__(256, 4)
void conv3x3_off(const float* __restrict__ in,  // [B,H,W,CIN]
                 const float* __restrict__ w,   // [COUT,CIN,3,3]
                 const float* __restrict__ bias,
                 float* __restrict__ out,       // [B,H,W,20]
                 int B, int H, int W) {
  constexpr int OC = COUT / NSPLIT;
  __shared__ float ws[9 * CIN * OC];
  int obase = blockIdx.y * OC;
  for (int t = threadIdx.x; t < 9 * CIN * OC; t += 256) {
    int k = t / (CIN * OC); int r = t % (CIN * OC);
    int c = r / OC; int o = r % OC;
    ws[t] = w[((obase + o) * CIN + c) * 9 + k];
  }
  __syncthreads();

  int gid = blockIdx.x * 256 + threadIdx.x;
  if (gid >= B * H * W) return;
  int x = gid % W; int t0 = gid / W; int y = t0 % H; int b = t0 / H;
  int HW = H * W;
  const float* inb = in + (size_t)b * HW * CIN;

  float acc[OC];
#pragma unroll
  for (int o = 0; o < OC; ++o) acc[o] = bias[obase + o];

#pragma unroll
  for (int ky = 0; ky < 3; ++ky) {
    int yy = y + ky - 1;
    if (yy < 0 || yy >= H) continue;
#pragma unroll
    for (int kx = 0; kx < 3; ++kx) {
      int xx = x + kx - 1;
      if (xx < 0 || xx >= W) continue;
      const float4* p4 = (const float4*)(inb + ((size_t)yy * W + xx) * CIN);
      int k = ky * 3 + kx;
#pragma unroll
      for (int c4 = 0; c4 < CIN / 4; ++c4) {
        float4 p = p4[c4];
        const float* pv = &p.x;
#pragma unroll
        for (int cc = 0; cc < 4; ++cc) {
          const float* wrow = &ws[(k * CIN + 4 * c4 + cc) * OC];
#pragma unroll
          for (int o = 0; o < OC; ++o) acc[o] = fmaf(wrow[o], pv[cc], acc[o]);
        }
      }
    }
  }

  float* op = out + (size_t)gid * 20 + obase;
#pragma unroll
  for (int o = 0; o < OC; ++o) op[o] = acc[o];
}

// ---- Two-phase patch-LDS deformable conv + ReLU (R9 structure).
// Phase1: threads=(px,quad) with px = tid/QT (quad-lanes of a pixel share its
// cacheline -> 16 lines per gather instr, was 64). Phase2: R9 verbatim.
template <int CIN, int COUT, int HW_, int PX>
__global__ void deform_patch(const float* __restrict__ in,     // [B,H,W,CIN]
                             const float* __restrict__ off_in, // [B*HW,20]
                             const float* __restrict__ wT,     // [9][CIN][COUT]
                             const float* __restrict__ bias,
                             float* __restrict__ out) {        // [B,COUT,H,W]
  constexpr int H = HW_, W = HW_, HW = H * W;
  constexpr int QT = CIN / 4;
  static_assert(PX * QT == 256, "block mapping");
  constexpr int PSTR = 9 * CIN + 4;       // per-px float stride (16B aligned)
  constexpr int PP = PX / 2;              // pixel pairs
  constexpr int OG = 256 / PP;            // out-channel groups
  constexpr int OPG = COUT / OG;          // outs per group
  static_assert(OPG == 4, "phase2 mapping");

  __shared__ __align__(16) float offs[PX * 20];
  __shared__ __align__(16) float patch[PX * PSTR];
  __shared__ __align__(16) float wsk[CIN * COUT];

  const int pixbase = blockIdx.x * PX;    // global pixel index over B*HW
  const int b = pixbase / HW;
  const int p0_in_b = pixbase - b * HW;
  const float* inb = in + (size_t)b * HW * CIN;

  // stage offsets (contiguous)
  {
    const float4* src = (const float4*)(off_in + (size_t)pixbase * 20);
    for (int t = threadIdx.x; t < PX * 20 / 4; t += 256)
      ((float4*)offs)[t] = src[t];
  }
  __syncthreads();

  // ---- phase 1: build patches (lane map: px = tid/QT, q = tid%QT)
  {
    int px = threadIdx.x / QT;
    int q  = threadIdx.x % QT;
    int pib = p0_in_b + px;
    int yi = pib / W, xi = pib % W;
#pragma unroll
    for (int k = 0; k < 9; ++k) {
      float py = (float)(yi + k / 3 - 1) + offs[px * 20 + 2 * k];
      float pxx = (float)(xi + k % 3 - 1) + offs[px * 20 + 2 * k + 1];
      float y0f = floorf(py), x0f = floorf(pxx);
      float fy = py - y0f, fx = pxx - x0f;
      int y0 = (int)y0f, x0 = (int)x0f, y1 = y0 + 1, x1 = x0 + 1;
      float vy0 = (y0 >= 0 && y0 < H) ? 1.f : 0.f;
      float vy1 = (y1 >= 0 && y1 < H) ? 1.f : 0.f;
      float vx0 = (x0 >= 0 && x0 < W) ? 1.f : 0.f;
      float vx1 = (x1 >= 0 && x1 < W) ? 1.f : 0.f;
      float w00 = (1.f - fy) * (1.f - fx) * vy0 * vx0;
      float w01 = (1.f - fy) * fx * vy0 * vx1;
      float w10 = fy * (1.f - fx) * vy1 * vx0;
      float w11 = fy * fx * vy1 * vx1;
      int cy0 = min(max(y0, 0), H - 1), cy1 = min(max(y1, 0), H - 1);
      int cx0 = min(max(x0, 0), W - 1), cx1 = min(max(x1, 0), W - 1);
      float4 A  = *(const float4*)(inb + ((size_t)cy0 * W + cx0) * CIN + 4 * q);
      float4 Bv = *(const float4*)(inb + ((size_t)cy0 * W + cx1) * CIN + 4 * q);
      float4 Cv = *(const float4*)(inb + ((size_t)cy1 * W + cx0) * CIN + 4 * q);
      float4 Dv = *(const float4*)(inb + ((size_t)cy1 * W + cx1) * CIN + 4 * q);
      float4 val;
      val.x = w00 * A.x + w01 * Bv.x + w10 * Cv.x + w11 * Dv.x;
      val.y = w00 * A.y + w01 * Bv.y + w10 * Cv.y + w11 * Dv.y;
      val.z = w00 * A.z + w01 * Bv.z + w10 * Cv.z + w11 * Dv.z;
      val.w = w00 * A.w + w01 * Bv.w + w10 * Cv.w + w11 * Dv.w;
      *(float4*)&patch[px * PSTR + k * CIN + 4 * q] = val;
    }
  }

  // ---- phase 2: GEMM from LDS (R9 verbatim)
  int pairIdx = threadIdx.x % PP;
  int og = threadIdx.x / PP;
  int obase = og * OPG;
  int px0 = pairIdx, px1 = pairIdx + PP;

  float acc0[OPG], acc1[OPG];
#pragma unroll
  for (int o = 0; o < OPG; ++o) { float bb = bias[obase + o]; acc0[o] = bb; acc1[o] = bb; }

  for (int k = 0; k < 9; ++k) {
    __syncthreads();  // (a) phase1 done / (b) previous wsk reads done
    {
      const float4* src = (const float4*)(wT + (size_t)k * CIN * COUT);
      for (int t = threadIdx.x; t < CIN * COUT / 4; t += 256)
        ((float4*)wsk)[t] = src[t];
    }
    __syncthreads();
#pragma unroll
    for (int c4 = 0; c4 < QT; ++c4) {
      float4 p0 = *(const float4*)&patch[px0 * PSTR + k * CIN + 4 * c4];
      float4 p1 = *(const float4*)&patch[px1 * PSTR + k * CIN + 4 * c4];
      const float* pv0 = &p0.x;
      const float* pv1 = &p1.x;
#pragma unroll
      for (int cc = 0; cc < 4; ++cc) {
        float4 wv = *(const float4*)&wsk[(4 * c4 + cc) * COUT + obase];
        acc0[0] = fmaf(wv.x, pv0[cc], acc0[0]);
        acc0[1] = fmaf(wv.y, pv0[cc], acc0[1]);
        acc0[2] = fmaf(wv.z, pv0[cc], acc0[2]);
        acc0[3] = fmaf(wv.w, pv0[cc], acc0[3]);
        acc1[0] = fmaf(wv.x, pv1[cc], acc1[0]);
        acc1[1] = fmaf(wv.y, pv1[cc], acc1[1]);
        acc1[2] = fmaf(wv.z, pv1[cc], acc1[2]);
        acc1[3] = fmaf(wv.w, pv1[cc], acc1[3]);
      }
    }
  }

  float* ob = out + ((size_t)b * COUT + obase) * HW + p0_in_b;
#pragma unroll
  for (int o = 0; o < OPG; ++o) {
    ob[(size_t)o * HW + px0] = fmaxf(acc0[o], 0.f);
    ob[(size_t)o * HW + px1] = fmaxf(acc1[o], 0.f);
  }
}

// ---- Adaptive avg pool 24->3 (8x8 bins) + fc(576->10), NCHW input.
__global__ void poolfc_kernel(const float* __restrict__ h,   // [B,64,24,24]
                              const float* __restrict__ wfc, // [10,576]
                              const float* __restrict__ bfc, // [10]
                              float* __restrict__ out) {     // [B,10]
  __shared__ float feat[576];
  int b = blockIdx.x;
  int f = threadIdx.x; // 576 threads
  int c = f / 9, ij = f % 9, i = ij / 3, j = ij % 3;
  const float* p = h + ((size_t)(b * 64 + c) * 24 + i * 8) * 24 + j * 8;
  float s = 0.f;
#pragma unroll
  for (int r = 0; r < 8; ++r)
#pragma unroll
    for (int q = 0; q < 8; ++q)
      s += p[r * 24 + q];
  feat[f] = s * (1.f / 64.f);
  __syncthreads();
  if (f < 10) {
    float acc = bfc[f];
    const float* wp = wfc + f * 576;
    for (int t = 0; t < 576; ++t) acc = fmaf(wp[t], feat[t], acc);
    out[b * 10 + f] = acc;
  }
}

extern "C" void kernel_launch(void* const* d_in, const int* in_sizes, int n_in,
                              void* d_out, int out_size, void* d_ws, size_t ws_size,
                              hipStream_t stream) {
  const float* x      = (const float*)d_in[0];
  const float* w_off1 = (const float*)d_in[1];
  const float* b_off1 = (const float*)d_in[2];
  const float* w1     = (const float*)d_in[3];
  const float* b1     = (const float*)d_in[4];
  const float* w_off2 = (const float*)d_in[5];
  const float* b_off2 = (const float*)d_in[6];
  const float* w2     = (const float*)d_in[7];
  const float* b2     = (const float*)d_in[8];
  const float* w_off3 = (const float*)d_in[9];
  const float* b_off3 = (const float*)d_in[10];
  const float* w3     = (const float*)d_in[11];
  const float* b3     = (const float*)d_in[12];
  const float* w_fc   = (const float*)d_in[13];
  const float* b_fc   = (const float*)d_in[14];
  float* out = (float*)d_out;

  char* ws = (char*)d_ws;
  float* A   = (float*)(ws);
  float* Cp  = (float*)(ws + 18874368);
  float* Bp  = (float*)(ws + 37748736);
  float* wT2 = (float*)(ws + 47185920);
  float* wT3 = (float*)(ws + 47185920 + 9 * 16 * 32 * 4);

  const int thr = 256;

  // Weight transposes (independent, run first)
  wtrans<16, 32><<<(9 * 16 * 32 + 255) / 256, thr, 0, stream>>>(w2, wT2);
  wtrans<32, 64><<<(9 * 32 * 64 + 255) / 256, thr, 0, stream>>>(w3, wT3);

  // Layer 1: fused offset+deform+relu -> A [64,16,96,96] NCHW (2 px/thread)
  deform1_fused<<<64 * 96 * 96 / 2 / thr, thr, 0, stream>>>(x, w_off1, b_off1, w1, b1, A);
  // pool -> Bp [64,48,48,16] NHWC
  {
    int total = 64 * 48 * 48 * 4;
    pool_nchw_to_nhwc<16, 96><<<(total + thr - 1) / thr, thr, 0, stream>>>(A, Bp);
  }

  // Layer 2: offset conv -> Cp [64,48,48,20] padded NHWC
  conv3x3_off<16, 18, 1><<<dim3(576, 1), thr, 0, stream>>>(Bp, w_off2, b_off2, Cp, 64, 48, 48);
  // deform + relu -> A [64,32,48,48] NCHW  (PX=64: 2304 blocks, 44KB LDS)
  deform_patch<16, 32, 48, 64><<<64 * 48 * 48 / 64, thr, 0, stream>>>(Bp, Cp, wT2, b2, A);
  // pool -> Bp [64,24,24,32] NHWC
  {
    int total = 64 * 24 * 24 * 8;
    pool_nchw_to_nhwc<32, 48><<<(total + thr - 1) / thr, thr, 0, stream>>>(A, Bp);
  }

  // Layer 3: offset conv -> Cp [64,24,24,20] padded NHWC
  conv3x3_off<32, 18, 3><<<dim3(144, 3), thr, 0, stream>>>(Bp, w_off3, b_off3, Cp, 64, 24, 24);
  // deform + relu -> A [64,64,24,24] NCHW  (PX=32: 1152 blocks, 47KB LDS)
  deform_patch<32, 64, 24, 32><<<64 * 24 * 24 / 32, thr, 0, stream>>>(Bp, Cp, wT3, b3, A);

  // avgpool(3x3) + fc -> out [64,10]
  poolfc_kernel<<<64, 576, 0, stream>>>(A, w_fc, b_fc, out);
}

// Round 16
// 172.864 us; speedup vs baseline: 6.2301x; 1.0186x over previous
//
#include <hip/hip_runtime.h>
#include <math.h>

// ---------------------------------------------------------------------------
// PermutedNetwork, R16 = R15/R12 + KCHUNK=3 weight staging in the L2 deform.
// R15 profile: L2 deform 42us = pipe-sum (VALU ~12 + LDS ~23 + VMEM ~8) plus
// 9 exposed barrier-bracketed weight-stage latencies. KCHUNK=3 stages 3
// k-slices per round: exposed latencies 9->3, barriers 18->6, LDS 48KB
// (still 3 blk/CU), NO new register state (R13/R14 spill lesson respected).
// L3 deform: KCHUNK=1 == R12 verbatim (bigger chunk would cost occupancy).
// ---------------------------------------------------------------------------

// ---- Weight transpose: w[o][c][k] -> wT[k][c][o] (run once, tiny).
template <int CIN, int COUT>
__global__ void wtrans(const float* __restrict__ w, float* __restrict__ wT) {
  int t = blockIdx.x * 256 + threadIdx.x;
  if (t >= 9 * CIN * COUT) return;
  int k = t / (CIN * COUT);
  int r = t % (CIN * COUT);
  int c = r / COUT;
  int o = r % COUT;
  wT[t] = w[(o * CIN + c) * 9 + k];
}

// ---- Layer 1: fused offset-conv + deform + relu, CIN=1. 2 pixels/thread.
__global__ void deform1_fused(const float* __restrict__ x,    // [64,96,96]
                              const float* __restrict__ woff, // [18,1,3,3]
                              const float* __restrict__ boff, // [18]
                              const float* __restrict__ w1,   // [16,1,3,3]
                              const float* __restrict__ b1,   // [16]
                              float* __restrict__ out) {      // [64,16,96,96]
  const int H = 96, W = 96, HW = H * W;
  __shared__ float wos[9 * 18];
  __shared__ __align__(16) float ws1[9 * 16];
  for (int t = threadIdx.x; t < 9 * 18; t += 256) { int k = t / 18, tc = t % 18; wos[t] = woff[tc * 9 + k]; }
  for (int t = threadIdx.x; t < 9 * 16; t += 256) { int k = t / 16, o = t % 16; ws1[t] = w1[o * 9 + k]; }
  __syncthreads();

  int gid = blockIdx.x * 256 + threadIdx.x;
  int p2 = gid % (HW / 2);
  int b  = gid / (HW / 2);
  int xi0 = (2 * p2) % W, yi = (2 * p2) / W;
  const float* xb = x + (size_t)b * HW;

  float v[3][4];
#pragma unroll
  for (int r = 0; r < 3; ++r) {
    int yy = yi + r - 1;
    float my = (yy >= 0 && yy < H) ? 1.f : 0.f;
    int cy = min(max(yy, 0), H - 1);
#pragma unroll
    for (int c = 0; c < 4; ++c) {
      int xx = xi0 + c - 1;
      float mx = (xx >= 0 && xx < W) ? 1.f : 0.f;
      int cx = min(max(xx, 0), W - 1);
      v[r][c] = xb[cy * W + cx] * (my * mx);
    }
  }

  float off0[18], off1[18];
#pragma unroll
  for (int tc = 0; tc < 18; ++tc) { float bb = boff[tc]; off0[tc] = bb; off1[tc] = bb; }
#pragma unroll
  for (int r = 0; r < 3; ++r)
#pragma unroll
    for (int c = 0; c < 3; ++c) {
      float t0 = v[r][c], t1 = v[r][c + 1];
      const float2* wv = (const float2*)&wos[(r * 3 + c) * 18];
#pragma unroll
      for (int tt = 0; tt < 9; ++tt) {
        float2 ww = wv[tt];
        off0[2 * tt]     = fmaf(ww.x, t0, off0[2 * tt]);
        off0[2 * tt + 1] = fmaf(ww.y, t0, off0[2 * tt + 1]);
        off1[2 * tt]     = fmaf(ww.x, t1, off1[2 * tt]);
        off1[2 * tt + 1] = fmaf(ww.y, t1, off1[2 * tt + 1]);
      }
    }

  float acc0[16], acc1[16];
#pragma unroll
  for (int o = 0; o < 16; ++o) { float bb = b1[o]; acc0[o] = bb; acc1[o] = bb; }

#pragma unroll
  for (int k = 0; k < 9; ++k) {
    int dky = k / 3 - 1, dkx = k % 3 - 1;
    float val0, val1;
    {
      float py = (float)(yi + dky) + off0[2 * k];
      float px = (float)(xi0 + dkx) + off0[2 * k + 1];
      float y0f = floorf(py), x0f = floorf(px);
      float fy = py - y0f, fx = px - x0f;
      int y0 = (int)y0f, x0 = (int)x0f, y1 = y0 + 1, x1 = x0 + 1;
      float vy0 = (y0 >= 0 && y0 < H) ? 1.f : 0.f;
      float vy1 = (y1 >= 0 && y1 < H) ? 1.f : 0.f;
      float vx0 = (x0 >= 0 && x0 < W) ? 1.f : 0.f;
      float vx1 = (x1 >= 0 && x1 < W) ? 1.f : 0.f;
      float w00 = (1.f - fy) * (1.f - fx) * vy0 * vx0;
      float w01 = (1.f - fy) * fx * vy0 * vx1;
      float w10 = fy * (1.f - fx) * vy1 * vx0;
      float w11 = fy * fx * vy1 * vx1;
      int cy0 = min(max(y0, 0), H - 1), cy1 = min(max(y1, 0), H - 1);
      int cx0 = min(max(x0, 0), W - 1), cx1 = min(max(x1, 0), W - 1);
      float a = xb[cy0 * W + cx0], bb = xb[cy0 * W + cx1];
      float c = xb[cy1 * W + cx0], d = xb[cy1 * W + cx1];
      val0 = w00 * a + w01 * bb + w10 * c + w11 * d;
    }
    {
      float py = (float)(yi + dky) + off1[2 * k];
      float px = (float)(xi0 + 1 + dkx) + off1[2 * k + 1];
      float y0f = floorf(py), x0f = floorf(px);
      float fy = py - y0f, fx = px - x0f;
      int y0 = (int)y0f, x0 = (int)x0f, y1 = y0 + 1, x1 = x0 + 1;
      float vy0 = (y0 >= 0 && y0 < H) ? 1.f : 0.f;
      float vy1 = (y1 >= 0 && y1 < H) ? 1.f : 0.f;
      float vx0 = (x0 >= 0 && x0 < W) ? 1.f : 0.f;
      float vx1 = (x1 >= 0 && x1 < W) ? 1.f : 0.f;
      float w00 = (1.f - fy) * (1.f - fx) * vy0 * vx0;
      float w01 = (1.f - fy) * fx * vy0 * vx1;
      float w10 = fy * (1.f - fx) * vy1 * vx0;
      float w11 = fy * fx * vy1 * vx1;
      int cy0 = min(max(y0, 0), H - 1), cy1 = min(max(y1, 0), H - 1);
      int cx0 = min(max(x0, 0), W - 1), cx1 = min(max(x1, 0), W - 1);
      float a = xb[cy0 * W + cx0], bb = xb[cy0 * W + cx1];
      float c = xb[cy1 * W + cx0], d = xb[cy1 * W + cx1];
      val1 = w00 * a + w01 * bb + w10 * c + w11 * d;
    }
    const float4* wv = (const float4*)&ws1[k * 16];
#pragma unroll
    for (int q = 0; q < 4; ++q) {
      float4 w4 = wv[q];
      acc0[4 * q + 0] = fmaf(w4.x, val0, acc0[4 * q + 0]);
      acc0[4 * q + 1] = fmaf(w4.y, val0, acc0[4 * q + 1]);
      acc0[4 * q + 2] = fmaf(w4.z, val0, acc0[4 * q + 2]);
      acc0[4 * q + 3] = fmaf(w4.w, val0, acc0[4 * q + 3]);
      acc1[4 * q + 0] = fmaf(w4.x, val1, acc1[4 * q + 0]);
      acc1[4 * q + 1] = fmaf(w4.y, val1, acc1[4 * q + 1]);
      acc1[4 * q + 2] = fmaf(w4.z, val1, acc1[4 * q + 2]);
      acc1[4 * q + 3] = fmaf(w4.w, val1, acc1[4 * q + 3]);
    }
  }

  float* op = out + (size_t)b * 16 * HW + (size_t)yi * W + xi0;
#pragma unroll
  for (int o = 0; o < 16; ++o) {
    float2 r = make_float2(fmaxf(acc0[o], 0.f), fmaxf(acc1[o], 0.f));
    *(float2*)(op + (size_t)o * HW) = r;
  }
}

// ---- 2x2 maxpool, NCHW in -> NHWC out.
template <int C, int HI>
__global__ void pool_nchw_to_nhwc(const float* __restrict__ in,  // [B,C,HI,HI]
                                  float* __restrict__ out) {     // [B,HO,HO,C]
  const int HO = HI / 2, C4 = C / 4;
  int gid = blockIdx.x * blockDim.x + threadIdx.x;
  if (gid >= 64 * HO * HO * C4) return;
  int c4 = gid % C4;
  int t = gid / C4;
  int x = t % HO; t /= HO;
  int y = t % HO;
  int b = t / HO;
  float4 r;
  float* rp = &r.x;
#pragma unroll
  for (int cc = 0; cc < 4; ++cc) {
    int c = c4 * 4 + cc;
    const float* p = in + ((size_t)(b * C + c) * HI + 2 * y) * HI + 2 * x;
    rp[cc] = fmaxf(fmaxf(p[0], p[1]), fmaxf(p[HI], p[HI + 1]));
  }
  *(float4*)(out + (((size_t)b * HO + y) * HO + x) * C + c4 * 4) = r;
}

// ---- 3x3 conv for offsets: NHWC in, PADDED NHWC out [B,H,W,20].
template <int CIN, int COUT, int NSPLIT>
__global__ __launch_bounds__(256, 4)
void conv3x3_off(const float* __restrict__ in,  // [B,H,W,CIN]
                 const float* __restrict__ w,   // [COUT,CIN,3,3]
                 const float* __restrict__ bias,
                 float* __restrict__ out,       // [B,H,W,20]
                 int B, int H, int W) {
  constexpr int OC = COUT / NSPLIT;
  __shared__ float ws[9 * CIN * OC];
  int obase = blockIdx.y * OC;
  for (int t = threadIdx.x; t < 9 * CIN * OC; t += 256) {
    int k = t / (CIN * OC); int r = t % (CIN * OC);
    int c = r / OC; int o = r % OC;
    ws[t] = w[((obase + o) * CIN + c) * 9 + k];
  }
  __syncthreads();

  int gid = blockIdx.x * 256 + threadIdx.x;
  if (gid >= B * H * W) return;
  int x = gid % W; int t0 = gid / W; int y = t0 % H; int b = t0 / H;
  int HW = H * W;
  const float* inb = in + (size_t)b * HW * CIN;

  float acc[OC];
#pragma unroll
  for (int o = 0; o < OC; ++o) acc[o] = bias[obase + o];

#pragma unroll
  for (int ky = 0; ky < 3; ++ky) {
    int yy = y + ky - 1;
    if (yy < 0 || yy >= H) continue;
#pragma unroll
    for (int kx = 0; kx < 3; ++kx) {
      int xx = x + kx - 1;
      if (xx < 0 || xx >= W) continue;
      const float4* p4 = (const float4*)(inb + ((size_t)yy * W + xx) * CIN);
      int k = ky * 3 + kx;
#pragma unroll
      for (int c4 = 0; c4 < CIN / 4; ++c4) {
        float4 p = p4[c4];
        const float* pv = &p.x;
#pragma unroll
        for (int cc = 0; cc < 4; ++cc) {
          const float* wrow = &ws[(k * CIN + 4 * c4 + cc) * OC];
#pragma unroll
          for (int o = 0; o < OC; ++o) acc[o] = fmaf(wrow[o], pv[cc], acc[o]);
        }
      }
    }
  }

  float* op = out + (size_t)gid * 20 + obase;
#pragma unroll
  for (int o = 0; o < OC; ++o) op[o] = acc[o];
}

// ---- Two-phase patch-LDS deformable conv + ReLU (R12 structure, KCHUNK
// weight staging: KCHUNK k-slices staged per barrier round).
template <int CIN, int COUT, int HW_, int PX, int KCHUNK>
__global__ void deform_patch(const float* __restrict__ in,     // [B,H,W,CIN]
                             const float* __restrict__ off_in, // [B*HW,20]
                             const float* __restrict__ wT,     // [9][CIN][COUT]
                             const float* __restrict__ bias,
                             float* __restrict__ out) {        // [B,COUT,H,W]
  constexpr int H = HW_, W = HW_, HW = H * W;
  constexpr int QT = CIN / 4;
  static_assert(PX * QT == 256, "block mapping");
  constexpr int PSTR = 9 * CIN + 4;       // per-px float stride (16B aligned)
  constexpr int PP = PX / 2;              // pixel pairs
  constexpr int OG = 256 / PP;            // out-channel groups
  constexpr int OPG = COUT / OG;          // outs per group
  static_assert(OPG == 4, "phase2 mapping");
  static_assert(9 % KCHUNK == 0, "chunking");
  constexpr int WN = CIN * COUT;          // weight floats per k

  __shared__ __align__(16) float offs[PX * 20];
  __shared__ __align__(16) float patch[PX * PSTR];
  __shared__ __align__(16) float wsk[KCHUNK * WN];

  const int pixbase = blockIdx.x * PX;    // global pixel index over B*HW
  const int b = pixbase / HW;
  const int p0_in_b = pixbase - b * HW;
  const float* inb = in + (size_t)b * HW * CIN;

  // stage offsets (contiguous)
  {
    const float4* src = (const float4*)(off_in + (size_t)pixbase * 20);
    for (int t = threadIdx.x; t < PX * 20 / 4; t += 256)
      ((float4*)offs)[t] = src[t];
  }
  __syncthreads();

  // ---- phase 1: build patches (lane map: px = tid/QT, q = tid%QT)
  {
    int px = threadIdx.x / QT;
    int q  = threadIdx.x % QT;
    int pib = p0_in_b + px;
    int yi = pib / W, xi = pib % W;
#pragma unroll
    for (int k = 0; k < 9; ++k) {
      float py = (float)(yi + k / 3 - 1) + offs[px * 20 + 2 * k];
      float pxx = (float)(xi + k % 3 - 1) + offs[px * 20 + 2 * k + 1];
      float y0f = floorf(py), x0f = floorf(pxx);
      float fy = py - y0f, fx = pxx - x0f;
      int y0 = (int)y0f, x0 = (int)x0f, y1 = y0 + 1, x1 = x0 + 1;
      float vy0 = (y0 >= 0 && y0 < H) ? 1.f : 0.f;
      float vy1 = (y1 >= 0 && y1 < H) ? 1.f : 0.f;
      float vx0 = (x0 >= 0 && x0 < W) ? 1.f : 0.f;
      float vx1 = (x1 >= 0 && x1 < W) ? 1.f : 0.f;
      float w00 = (1.f - fy) * (1.f - fx) * vy0 * vx0;
      float w01 = (1.f - fy) * fx * vy0 * vx1;
      float w10 = fy * (1.f - fx) * vy1 * vx0;
      float w11 = fy * fx * vy1 * vx1;
      int cy0 = min(max(y0, 0), H - 1), cy1 = min(max(y1, 0), H - 1);
      int cx0 = min(max(x0, 0), W - 1), cx1 = min(max(x1, 0), W - 1);
      float4 A  = *(const float4*)(inb + ((size_t)cy0 * W + cx0) * CIN + 4 * q);
      float4 Bv = *(const float4*)(inb + ((size_t)cy0 * W + cx1) * CIN + 4 * q);
      float4 Cv = *(const float4*)(inb + ((size_t)cy1 * W + cx0) * CIN + 4 * q);
      float4 Dv = *(const float4*)(inb + ((size_t)cy1 * W + cx1) * CIN + 4 * q);
      float4 val;
      val.x = w00 * A.x + w01 * Bv.x + w10 * Cv.x + w11 * Dv.x;
      val.y = w00 * A.y + w01 * Bv.y + w10 * Cv.y + w11 * Dv.y;
      val.z = w00 * A.z + w01 * Bv.z + w10 * Cv.z + w11 * Dv.z;
      val.w = w00 * A.w + w01 * Bv.w + w10 * Cv.w + w11 * Dv.w;
      *(float4*)&patch[px * PSTR + k * CIN + 4 * q] = val;
    }
  }

  // ---- phase 2: GEMM from LDS, KCHUNK k-slices of weights per stage round
  int pairIdx = threadIdx.x % PP;
  int og = threadIdx.x / PP;
  int obase = og * OPG;
  int px0 = pairIdx, px1 = pairIdx + PP;

  float acc0[OPG], acc1[OPG];
#pragma unroll
  for (int o = 0; o < OPG; ++o) { float bb = bias[obase + o]; acc0[o] = bb; acc1[o] = bb; }

  for (int kc = 0; kc < 9; kc += KCHUNK) {
    __syncthreads();  // (a) phase1 done / (b) previous wsk reads done
    {
      const float4* src = (const float4*)(wT + (size_t)kc * WN);
      for (int t = threadIdx.x; t < KCHUNK * WN / 4; t += 256)
        ((float4*)wsk)[t] = src[t];
    }
    __syncthreads();
    for (int kk = 0; kk < KCHUNK; ++kk) {
      int k = kc + kk;
#pragma unroll
      for (int c4 = 0; c4 < QT; ++c4) {
        float4 p0 = *(const float4*)&patch[px0 * PSTR + k * CIN + 4 * c4];
        float4 p1 = *(const float4*)&patch[px1 * PSTR + k * CIN + 4 * c4];
        const float* pv0 = &p0.x;
        const float* pv1 = &p1.x;
#pragma unroll
        for (int cc = 0; cc < 4; ++cc) {
          float4 wv = *(const float4*)&wsk[(kk * CIN + 4 * c4 + cc) * COUT + obase];
          acc0[0] = fmaf(wv.x, pv0[cc], acc0[0]);
          acc0[1] = fmaf(wv.y, pv0[cc], acc0[1]);
          acc0[2] = fmaf(wv.z, pv0[cc], acc0[2]);
          acc0[3] = fmaf(wv.w, pv0[cc], acc0[3]);
          acc1[0] = fmaf(wv.x, pv1[cc], acc1[0]);
          acc1[1] = fmaf(wv.y, pv1[cc], acc1[1]);
          acc1[2] = fmaf(wv.z, pv1[cc], acc1[2]);
          acc1[3] = fmaf(wv.w, pv1[cc], acc1[3]);
        }
      }
    }
  }

  float* ob = out + ((size_t)b * COUT + obase) * HW + p0_in_b;
#pragma unroll
  for (int o = 0; o < OPG; ++o) {
    ob[(size_t)o * HW + px0] = fmaxf(acc0[o], 0.f);
    ob[(size_t)o * HW + px1] = fmaxf(acc1[o], 0.f);
  }
}

// ---- Adaptive avg pool 24->3 (8x8 bins) + fc(576->10), NCHW input.
__global__ void poolfc_kernel(const float* __restrict__ h,   // [B,64,24,24]
                              const float* __restrict__ wfc, // [10,576]
                              const float* __restrict__ bfc, // [10]
                              float* __restrict__ out) {     // [B,10]
  __shared__ float feat[576];
  int b = blockIdx.x;
  int f = threadIdx.x; // 576 threads
  int c = f / 9, ij = f % 9, i = ij / 3, j = ij % 3;
  const float* p = h + ((size_t)(b * 64 + c) * 24 + i * 8) * 24 + j * 8;
  float s = 0.f;
#pragma unroll
  for (int r = 0; r < 8; ++r)
#pragma unroll
    for (int q = 0; q < 8; ++q)
      s += p[r * 24 + q];
  feat[f] = s * (1.f / 64.f);
  __syncthreads();
  if (f < 10) {
    float acc = bfc[f];
    const float* wp = wfc + f * 576;
    for (int t = 0; t < 576; ++t) acc = fmaf(wp[t], feat[t], acc);
    out[b * 10 + f] = acc;
  }
}

extern "C" void kernel_launch(void* const* d_in, const int* in_sizes, int n_in,
                              void* d_out, int out_size, void* d_ws, size_t ws_size,
                              hipStream_t stream) {
  const float* x      = (const float*)d_in[0];
  const float* w_off1 = (const float*)d_in[1];
  const float* b_off1 = (const float*)d_in[2];
  const float* w1     = (const float*)d_in[3];
  const float* b1     = (const float*)d_in[4];
  const float* w_off2 = (const float*)d_in[5];
  const float* b_off2 = (const float*)d_in[6];
  const float* w2     = (const float*)d_in[7];
  const float* b2     = (const float*)d_in[8];
  const float* w_off3 = (const float*)d_in[9];
  const float* b_off3 = (const float*)d_in[10];
  const float* w3     = (const float*)d_in[11];
  const float* b3     = (const float*)d_in[12];
  const float* w_fc   = (const float*)d_in[13];
  const float* b_fc   = (const float*)d_in[14];
  float* out = (float*)d_out;

  char* ws = (char*)d_ws;
  float* A   = (float*)(ws);
  float* Cp  = (float*)(ws + 18874368);
  float* Bp  = (float*)(ws + 37748736);
  float* wT2 = (float*)(ws + 47185920);
  float* wT3 = (float*)(ws + 47185920 + 9 * 16 * 32 * 4);

  const int thr = 256;

  // Weight transposes (independent, run first)
  wtrans<16, 32><<<(9 * 16 * 32 + 255) / 256, thr, 0, stream>>>(w2, wT2);
  wtrans<32, 64><<<(9 * 32 * 64 + 255) / 256, thr, 0, stream>>>(w3, wT3);

  // Layer 1: fused offset+deform+relu -> A [64,16,96,96] NCHW (2 px/thread)
  deform1_fused<<<64 * 96 * 96 / 2 / thr, thr, 0, stream>>>(x, w_off1, b_off1, w1, b1, A);
  // pool -> Bp [64,48,48,16] NHWC
  {
    int total = 64 * 48 * 48 * 4;
    pool_nchw_to_nhwc<16, 96><<<(total + thr - 1) / thr, thr, 0, stream>>>(A, Bp);
  }

  // Layer 2: offset conv -> Cp [64,48,48,20] padded NHWC
  conv3x3_off<16, 18, 1><<<dim3(576, 1), thr, 0, stream>>>(Bp, w_off2, b_off2, Cp, 64, 48, 48);
  // deform + relu -> A [64,32,48,48] NCHW  (PX=64, KCHUNK=3: 48KB LDS, 3 blk/CU)
  deform_patch<16, 32, 48, 64, 3><<<64 * 48 * 48 / 64, thr, 0, stream>>>(Bp, Cp, wT2, b2, A);
  // pool -> Bp [64,24,24,32] NHWC
  {
    int total = 64 * 24 * 24 * 8;
    pool_nchw_to_nhwc<32, 48><<<(total + thr - 1) / thr, thr, 0, stream>>>(A, Bp);
  }

  // Layer 3: offset conv -> Cp [64,24,24,20] padded NHWC
  conv3x3_off<32, 18, 3><<<dim3(144, 3), thr, 0, stream>>>(Bp, w_off3, b_off3, Cp, 64, 24, 24);
  // deform + relu -> A [64,64,24,24] NCHW  (PX=32, KCHUNK=1 == R12: 47KB LDS)
  deform_patch<32, 64, 24, 32, 1><<<64 * 24 * 24 / 32, thr, 0, stream>>>(Bp, Cp, wT3, b3, A);

  // avgpool(3x3) + fc -> out [64,10]
  poolfc_kernel<<<64, 576, 0, stream>>>(A, w_fc, b_fc, out);
}